// Round 6
// baseline (202.910 us; speedup 1.0000x reference)
//
#include <hip/hip_runtime.h>
#include <math.h>

// Problem constants (from reference)
#define BB 8
#define SS 64
#define VV 50257
#define PP 200
#define NW 1571                          // ceil(VV/32) mask words per sequence
#define CH 4                             // chunks per row
#define NT2 256                          // threads per chunk block
#define IT2 13                           // float4 iters per thread per chunk
#define NBQ (NT2 * IT2)                  // 3328 float4 per chunk; 4*3328 >= 12565
constexpr float RP   = 1.2f;
constexpr float RPI  = 1.0f / 1.2f;
constexpr float TINV = 1.0f / 0.6f;      // 1/temperature
constexpr float RPT  = RP * TINV;        // fused factor: exp(x * f)
constexpr float RPIT = RPI * TINV;

typedef float f32x4 __attribute__((ext_vector_type(4)));

// ---------------------------------------------------------------------------
// DECOUPLED TWO-DISPATCH STREAMING.
//
// r0/r2/r4 all converged to the same machine (the compiler rewrites register
// retention into reload+recompute; VGPR 40-48 every time) and all plateaued
// at 65-73us = 2x the 206MB/6.3TB/s floor. Shared defect: 512 lockstep
// 1024-thread blocks serialize chip-wide into read-phase then write-phase
// (HBM R and W pipes never overlap) with vmcnt-draining barriers coupling 16
// waves at a time.
//
// Fix: split into two pure streaming kernels with small (256-thr) blocks:
//  k_sum  : 64 dedupe blocks (LDS-dedupe prev tokens; per-b delta
//           = e^{adj}-e^{raw} summed in LDS; publish {mask,allneg} bitfields
//           to ws) + 2048 chunk blocks (1/4 row each, exp-sum -> plain store
//           wsum[row][chunk]). Deterministic, no zeroing needed (all 5 slots
//           rewritten every iteration).
//  k_scale: 2048 chunk blocks; li = 1/(sum of 5 slots); every element
//           computes its penalized-or-not value DIRECTLY from the bitfields
//           (penalty idempotent; dedupe only affects the sum delta) -> the
//           scatter-overwrite pass and all barriers vanish. Reads (L3-hot)
//           and writes overlap chip-wide.
//
// ws layout: [0,16KB) float wsum[512][8] (slots 0-3 chunk sums, 4 delta);
//            [16KB, 16KB+64*1571*8) uint2 {mask,allneg} per (s,word).
// ---------------------------------------------------------------------------

__device__ __forceinline__ float scale1(float x, int v, const uint2* brow,
                                        float li) {
    uint2 c = brow[v >> 5];
    unsigned sh = (unsigned)v & 31u;
    bool bit = (c.x >> sh) & 1u;
    bool ab  = (c.y >> sh) & 1u;
    float f = bit ? (ab ? RPT : RPIT) : TINV;
    return __expf(x * f) * li;
}

__global__ __launch_bounds__(NT2) void k_sum(
        const float* __restrict__ logits,
        const int*   __restrict__ prev,
        float*       __restrict__ wsum,
        uint2*       __restrict__ bits) {
    const int blk = blockIdx.x;
    const int tid = threadIdx.x;

    __shared__ unsigned lmask[NW];
    __shared__ unsigned lall[NW];
    __shared__ float    dsum[BB];
    __shared__ float    wpart[NT2 / 64];

    if (blk < SS) {
        // ---- dedupe block for sequence s = blk --------------------------
        const int s = blk;
        for (int i = tid; i < NW; i += NT2) { lmask[i] = 0u; lall[i] = 0u; }
        if (tid < BB) dsum[tid] = 0.f;
        __syncthreads();

        if (tid < PP) {
            int tok = prev[s * PP + tid];
            unsigned bit = 1u << (tok & 31);
            unsigned old = atomicOr(&lmask[tok >> 5], bit);
            if (!(old & bit)) {                       // winner per distinct tok
                float lv[BB];
                bool alln = true;
                #pragma unroll
                for (int b = 0; b < BB; ++b) {
                    lv[b] = logits[((size_t)(b * SS + s)) * VV + tok];
                    alln = alln && (lv[b] < 0.f);
                }
                if (alln) atomicOr(&lall[tok >> 5], bit);
                const float ft = alln ? RPT : RPIT;
                #pragma unroll
                for (int b = 0; b < BB; ++b) {
                    float d = __expf(lv[b] * ft) - __expf(lv[b] * TINV);
                    atomicAdd(&dsum[b], d);           // LDS f32 atomic
                }
            }
        }
        __syncthreads();

        uint2* brow = bits + (size_t)s * NW;
        for (int i = tid; i < NW; i += NT2)
            brow[i] = make_uint2(lmask[i], lall[i]);
        if (tid < BB) wsum[(tid * SS + s) * 8 + 4] = dsum[tid];
        return;
    }

    // ---- streaming chunk block ------------------------------------------
    const int cblk  = blk - SS;
    const int row   = cblk >> 2;
    const int chunk = cblk & 3;
    const int a0 = (4 - (row & 3)) & 3;          // head elems to 16B align
    const int nb = (VV - a0) >> 2;               // float4 body count
    const float* rowp = logits + (size_t)row * VV;
    const f32x4* body = (const f32x4*)(rowp + a0);

    float acc = 0.f;
    #pragma unroll
    for (int k = 0; k < IT2; ++k) {
        int fi = chunk * NBQ + k * NT2 + tid;
        if (fi < nb) {
            f32x4 x = body[fi];
            acc += __expf(x.x * TINV) + __expf(x.y * TINV)
                 + __expf(x.z * TINV) + __expf(x.w * TINV);
        }
    }
    if (chunk == 0) {
        const int tail   = VV - a0 - (nb << 2);
        const int tstart = a0 + (nb << 2);
        if (tid < a0)                 acc += __expf(rowp[tid] * TINV);
        if (tid >= 4 && tid < 4 + tail)
            acc += __expf(rowp[tstart + tid - 4] * TINV);
    }
    #pragma unroll
    for (int off = 1; off < 64; off <<= 1) acc += __shfl_xor(acc, off);
    const int wave = tid >> 6, lane = tid & 63;
    if (lane == 0) wpart[wave] = acc;
    __syncthreads();
    if (tid == 0)
        wsum[row * 8 + chunk] = (wpart[0] + wpart[1]) + (wpart[2] + wpart[3]);
}

__global__ __launch_bounds__(NT2) void k_scale(
        const float* __restrict__ logits,
        const float* __restrict__ wsum,
        const uint2* __restrict__ bits,
        float*       __restrict__ out) {
    const int blk   = blockIdx.x;
    const int tid   = threadIdx.x;
    const int row   = blk >> 2;
    const int chunk = blk & 3;
    const int s     = row & (SS - 1);
    const int a0 = (4 - (row & 3)) & 3;
    const int nb = (VV - a0) >> 2;
    const float* rowp = logits + (size_t)row * VV;
    float*       orow = out    + (size_t)row * VV;
    const f32x4* body  = (const f32x4*)(rowp + a0);
    f32x4*       obody = (f32x4*)(orow + a0);
    const uint2* brow  = bits + (size_t)s * NW;

    const float* wr = wsum + row * 8;
    const float S  = ((wr[0] + wr[1]) + (wr[2] + wr[3])) + wr[4];
    const float li = 1.0f / S;

    #pragma unroll
    for (int k = 0; k < IT2; ++k) {
        int fi = chunk * NBQ + k * NT2 + tid;
        if (fi < nb) {
            f32x4 x = body[fi];
            const int vb = a0 + (fi << 2);
            const int w0 = vb >> 5, w3 = (vb + 3) >> 5;
            uint2 c0 = brow[w0];
            uint2 c3 = brow[w3];
            f32x4 o;
            #pragma unroll
            for (int j = 0; j < 4; ++j) {
                const int v = vb + j;
                uint2 c = ((v >> 5) == w0) ? c0 : c3;
                unsigned sh = (unsigned)v & 31u;
                bool bit = (c.x >> sh) & 1u;
                bool ab  = (c.y >> sh) & 1u;
                float f = bit ? (ab ? RPT : RPIT) : TINV;
                o[j] = __expf(x[j] * f) * li;
            }
            obody[fi] = o;
        }
    }
    if (chunk == 0) {
        const int tail   = VV - a0 - (nb << 2);
        const int tstart = a0 + (nb << 2);
        if (tid < a0)
            orow[tid] = scale1(rowp[tid], tid, brow, li);
        if (tid >= 4 && tid < 4 + tail) {
            int v = tstart + tid - 4;
            orow[v] = scale1(rowp[v], v, brow, li);
        }
    }
}

// ---------------------------------------------------------------------------
// Fallback (r4 single-kernel) if the workspace is too small for the bitfields.
// ---------------------------------------------------------------------------
#define NMASK 1571
#define NT 1024
#define ITER 13

__global__ __launch_bounds__(NT) void sch_fused_kernel(
        const float* __restrict__ logits,
        const int*   __restrict__ prev,
        float*       __restrict__ out) {
    __shared__ unsigned mask[NMASK];
    __shared__ float ss[16];
    __shared__ float bc_li;

    const int bs  = blockIdx.x;
    const int s   = bs & (SS - 1);
    const int tid = threadIdx.x;
    const float* row  = logits + (size_t)bs * VV;
    float*       orow = out    + (size_t)bs * VV;

    const int a0   = (4 - (bs & 3)) & 3;
    const int nb   = (VV - a0) >> 2;
    const int tail = VV - a0 - (nb << 2);
    const int tstart = a0 + (nb << 2);
    const f32x4* body = (const f32x4*)(row + a0);
    const bool has_head = (tid < a0);
    const bool has_tail = (tid >= 4 && tid < 4 + tail);

    int   vtok = -1;
    float lv[BB];
    if (tid < PP) {
        vtok = prev[s * PP + tid];
        #pragma unroll
        for (int b = 0; b < BB; ++b)
            lv[b] = logits[((size_t)(b * SS + s)) * VV + vtok];
    }
    for (int i = tid; i < NMASK; i += NT) mask[i] = 0u;
    __syncthreads();

    bool winner = false;
    if (tid < PP) {
        unsigned bit = 1u << (vtok & 31);
        unsigned old = atomicOr(&mask[vtok >> 5], bit);
        winner = (old & bit) == 0u;
    }

    float accx = 0.f, accy = 0.f, accz = 0.f, accw = 0.f;
    #pragma unroll
    for (int k = 0; k < ITER; ++k) {
        int i = tid + k * NT;
        if (i < nb) {
            f32x4 x = body[i];
            accx += __expf(x.x * TINV);
            accy += __expf(x.y * TINV);
            accz += __expf(x.z * TINV);
            accw += __expf(x.w * TINV);
        }
    }
    float sum = (accx + accy) + (accz + accw);
    if (has_head) sum += __expf(row[tid] * TINV);
    if (has_tail) sum += __expf(row[tstart + tid - 4] * TINV);

    float eadj = 0.0f;
    if (winner) {
        bool all_neg = true;
        #pragma unroll
        for (int b = 0; b < BB; ++b) all_neg = all_neg && (lv[b] < 0.0f);
        const float myraw = lv[bs >> 6];
        const float adj   = all_neg ? myraw * RP : myraw / RP;
        eadj = __expf(adj * TINV);
        sum += eadj - __expf(myraw * TINV);
    }

    #pragma unroll
    for (int off = 1; off < 64; off <<= 1) sum += __shfl_xor(sum, off);
    const int wave = tid >> 6, lane = tid & 63;
    if (lane == 0) ss[wave] = sum;
    __syncthreads();
    if (tid == 0) {
        float S0 = ss[0];
        #pragma unroll
        for (int w = 1; w < 16; ++w) S0 += ss[w];
        bc_li = 1.0f / S0;
    }
    __syncthreads();
    const float li = bc_li;

    f32x4* obody = (f32x4*)(orow + a0);
    #pragma unroll
    for (int k = 0; k < ITER; ++k) {
        int i = tid + k * NT;
        if (i < nb) {
            f32x4 x = body[i];
            f32x4 o;
            o.x = __expf(x.x * TINV) * li;
            o.y = __expf(x.y * TINV) * li;
            o.z = __expf(x.z * TINV) * li;
            o.w = __expf(x.w * TINV) * li;
            obody[i] = o;
        }
    }
    if (has_head) orow[tid]              = __expf(row[tid] * TINV) * li;
    if (has_tail) orow[tstart + tid - 4] = __expf(row[tstart + tid - 4] * TINV) * li;

    __syncthreads();
    if (winner) orow[vtok] = eadj * li;
}

extern "C" void kernel_launch(void* const* d_in, const int* in_sizes, int n_in,
                              void* d_out, int out_size, void* d_ws, size_t ws_size,
                              hipStream_t stream) {
    const float* logits = (const float*)d_in[0];
    const int*   prev   = (const int*)d_in[1];
    float* out = (float*)d_out;

    const size_t need = 16384 + (size_t)SS * NW * sizeof(uint2);  // ~821 KB
    if (d_ws != nullptr && ws_size >= need) {
        float* wsum = (float*)d_ws;
        uint2* bits = (uint2*)((char*)d_ws + 16384);
        k_sum  <<<SS + BB * SS * CH, NT2, 0, stream>>>(logits, prev, wsum, bits);
        k_scale<<<     BB * SS * CH, NT2, 0, stream>>>(logits, wsum, bits, out);
    } else {
        sch_fused_kernel<<<BB * SS, NT, 0, stream>>>(logits, prev, out);
    }
}

// Round 8
// 198.074 us; speedup vs baseline: 1.0244x; 1.0244x over previous
//
#include <hip/hip_runtime.h>
#include <math.h>

// Problem constants (from reference)
#define BB 8
#define SS 64
#define VV 50257
#define PP 200
#define NW 1571                          // ceil(VV/32) mask words per sequence
#define NT 256                           // threads per block
#define IT 50                            // ceil(12564/256) float4 iters
constexpr float RP   = 1.2f;
constexpr float RPI  = 1.0f / 1.2f;
constexpr float TINV = 1.0f / 0.6f;      // 1/temperature
constexpr float RPT  = RP * TINV;        // exp(x*f) fused factors
constexpr float RPIT = RPI * TINV;

typedef float f32x4 __attribute__((ext_vector_type(4)));

// ---------------------------------------------------------------------------
// SINGLE-DISPATCH, PER-ROW INDEPENDENT BLOCKS.
//
// Ledger from r0-r6 (profiles): dur_us = ~122us of harness poison-fills
// (2 x 402MB @ 6.7 TB/s, fixed) + our kernels. r0 fused-1024thr = 65us;
// r6 two-dispatch = ~80us combined -- the split lost to dispatch drains +
// workspace traffic. Floor = 206MB HBM / 6.3TB/s ~= 33us (R and W share
// one HBM pool -- phase overlap buys nothing; overheads are everything).
//
// This version removes every overhead found so far:
//  - ONE dispatch, 512 blocks (one per (b,s) row), 256 thr: barriers couple
//    only 4 waves; the other block on the CU keeps streaming.
//  - Dedupe duplicated per row (x8 blocks share s): +~6.5MB scattered lines
//    (L2/L3-hot) in exchange for NO workspace, NO cross-block coupling.
//  - LDS mask zeroing happens BEFORE any vmem is issued -> its barrier is
//    free (r0 poison: barrier after issuing loads drains vmcnt(0)).
//  - Dedupe chain (prev token -> 8 scattered lv) issued before the sum
//    loop; resolved after it -> 2-deep HBM latency fully hidden.
//  - Write pass recomputes each element's penalty factor directly from the
//    LDS {mask, allneg} bitmasks (penalty is idempotent; dedupe only
//    affects the sum delta) -> scatter-overwrite pass and its barrier gone.
//  - nt stores: output never pollutes L3, so the write-pass re-read of the
//    input stays L3-resident (poison fill evicts it only between iters).
// ---------------------------------------------------------------------------

__global__ __launch_bounds__(NT) void k_row(
        const float* __restrict__ logits,
        const int*   __restrict__ prev,
        float*       __restrict__ out) {
    __shared__ unsigned lmask[NW];
    __shared__ unsigned lall[NW];
    __shared__ float    red[NT / 64];
    __shared__ float    bcli;

    const int bs  = blockIdx.x;          // bs = b*SS + s
    const int s   = bs & (SS - 1);
    const int b   = bs >> 6;
    const int tid = threadIdx.x;
    const float* row  = logits + (size_t)bs * VV;
    float*       orow = out    + (size_t)bs * VV;

    const int a0     = (4 - (bs & 3)) & 3;      // head elems to 16B align
    const int nb     = (VV - a0) >> 2;          // float4 body count
    const int tail   = VV - a0 - (nb << 2);
    const int tstart = a0 + (nb << 2);
    const f32x4* body = (const f32x4*)(row + a0);
    const bool hh = (tid < a0);
    const bool ht = (tid >= 4 && tid < 4 + tail);

    // ---- zero dedupe masks; barrier is cheap (no vmem outstanding) ----
    for (int i = tid; i < NW; i += NT) { lmask[i] = 0u; lall[i] = 0u; }
    __syncthreads();

    // ---- issue dedupe chain early (hidden under the sum stream) -------
    int   vtok = -1;
    float lv[BB];
    if (tid < PP) {
        vtok = prev[s * PP + tid];
        #pragma unroll
        for (int j = 0; j < BB; ++j)
            lv[j] = logits[((size_t)(j * SS + s)) * VV + vtok];
    }

    // ---- streaming sum pass -------------------------------------------
    float acc = 0.f;
    #pragma unroll
    for (int k = 0; k < IT; ++k) {
        int i = tid + k * NT;
        if (i < nb) {
            f32x4 x = body[i];
            acc += __expf(x.x * TINV) + __expf(x.y * TINV)
                 + __expf(x.z * TINV) + __expf(x.w * TINV);
        }
    }
    if (hh) acc += __expf(row[tid] * TINV);
    if (ht) acc += __expf(row[tstart + tid - 4] * TINV);

    // ---- dedupe resolve + this-row delta ------------------------------
    if (tid < PP) {
        unsigned bit = 1u << (vtok & 31);
        unsigned old = atomicOr(&lmask[vtok >> 5], bit);
        if (!(old & bit)) {                       // winner per distinct tok
            bool alln = true;
            #pragma unroll
            for (int j = 0; j < BB; ++j) alln = alln && (lv[j] < 0.f);
            if (alln) atomicOr(&lall[vtok >> 5], bit);
            const float ft = alln ? RPT : RPIT;
            acc += __expf(lv[b] * ft) - __expf(lv[b] * TINV);
        }
    }

    // ---- block reduce (4 waves; loads all consumed -> cheap drain) ----
    #pragma unroll
    for (int off = 1; off < 64; off <<= 1) acc += __shfl_xor(acc, off);
    if ((tid & 63) == 0) red[tid >> 6] = acc;
    __syncthreads();
    if (tid == 0) bcli = 1.0f / ((red[0] + red[1]) + (red[2] + red[3]));
    __syncthreads();
    const float li = bcli;

    // ---- write pass: factor from LDS bitmasks, nt store ---------------
    f32x4* obody = (f32x4*)(orow + a0);
    #pragma unroll
    for (int k = 0; k < IT; ++k) {
        int i = tid + k * NT;
        if (i < nb) {
            f32x4 x = body[i];                    // L3-hot re-read
            const int vb = a0 + (i << 2);
            const int w0 = vb >> 5, w3 = (vb + 3) >> 5;
            const unsigned m0 = lmask[w0], A0 = lall[w0];
            const unsigned m3 = lmask[w3], A3 = lall[w3];
            f32x4 o;
            #pragma unroll
            for (int j = 0; j < 4; ++j) {
                const int v = vb + j;
                const unsigned mm = ((v >> 5) == w0) ? m0 : m3;
                const unsigned aa = ((v >> 5) == w0) ? A0 : A3;
                const unsigned sh = (unsigned)v & 31u;
                const bool bit = (mm >> sh) & 1u;
                const bool ab  = (aa >> sh) & 1u;
                const float f  = bit ? (ab ? RPT : RPIT) : TINV;
                o[j] = __expf(x[j] * f) * li;
            }
            __builtin_nontemporal_store(o, &obody[i]);
        }
    }
    if (hh || ht) {
        const int v = hh ? tid : (tstart + tid - 4);
        const unsigned mm = lmask[v >> 5], aa = lall[v >> 5];
        const unsigned sh = (unsigned)v & 31u;
        const bool bit = (mm >> sh) & 1u;
        const bool ab  = (aa >> sh) & 1u;
        const float f  = bit ? (ab ? RPT : RPIT) : TINV;
        __builtin_nontemporal_store(__expf(row[v] * f) * li, &orow[v]);
    }
}

extern "C" void kernel_launch(void* const* d_in, const int* in_sizes, int n_in,
                              void* d_out, int out_size, void* d_ws, size_t ws_size,
                              hipStream_t stream) {
    const float* logits = (const float*)d_in[0];
    const int*   prev   = (const int*)d_in[1];
    float* out = (float*)d_out;

    k_row<<<BB * SS, NT, 0, stream>>>(logits, prev, out);
}